// Round 19
// baseline (51.979 us; speedup 1.0000x reference)
//
#include <hip/hip_runtime.h>
#include <hip/hip_bf16.h>
#include <stdint.h>

#define S_SCALE 30.0f
#define S_L2E_SC 0.33813165020835f  /* 30*log2(e)/128 : inputs scaled 8*16 */
#define N_ROWS 8192
#define D_DIM 256
#define C_CLS 10000
#define NCB 16

typedef __attribute__((ext_vector_type(4))) float f32x4;

static __device__ __forceinline__ void gl16(const void* g, void* l) {
  __builtin_amdgcn_global_load_lds(
      (const __attribute__((address_space(1))) void*)g,
      (__attribute__((address_space(3))) void*)l, 16, 0, 0);
}

static __device__ __forceinline__ long u2l(uint2 v) {
  union { uint2 u; long l; } x; x.u = v; return x.l;
}

// 16-lane (DPP-row) sum, VALU pipe only; all lanes receive the group sum.
static __device__ __forceinline__ float row_sum16(float v) {
  union { float f; int i; } u, w;
  u.f = v;
  w.i = __builtin_amdgcn_update_dpp(0, u.i, 0xB1, 0xF, 0xF, true);  u.f += w.f; // lane^1
  w.i = __builtin_amdgcn_update_dpp(0, u.i, 0x4E, 0xF, 0xF, true);  u.f += w.f; // lane^2
  w.i = __builtin_amdgcn_update_dpp(0, u.i, 0x141, 0xF, 0xF, true); u.f += w.f; // half-mirror
  w.i = __builtin_amdgcn_update_dpp(0, u.i, 0x140, 0xF, 0xF, true); u.f += w.f; // row-mirror
  return u.f;
}

// ---- fused prep (fp8 e4m3, pre-scaled): blocks <1280 convert W (x16) to
// PAIRED frag layout; rest L2-normalize x (x8) into A-frag layout + exact
// fp32 target logit. (Layouts identical to r18 -- verified absmax 0.0.)
// WbF8 (paired): [c16pair 0..319][kc 0..7][lane]16B; lane's 16B = even-c16
// frag 8B then odd-c16 frag 8B. Within a frag, lane=lk*16+lr holds
// W[col=c16*16+lr][k=kc*32+lk*8 ..+8]; cols >= C_CLS zero (exp2(0)=1,
// subtracted in k_loss1).
// xnb8: [panel 0..63] 32KB frag blocks: byte (r16*8+kc)*512 + lane*8 within
// panel (row = panel*128 + r16*16 + lr).
__global__ __launch_bounds__(256) void k_prep(const float* __restrict__ x,
                                              const float* __restrict__ W,
                                              const int* __restrict__ target,
                                              unsigned char* __restrict__ xnb8,
                                              unsigned char* __restrict__ WbF8,
                                              float* __restrict__ tgt) {
  if (blockIdx.x < 1280) {
    int gidx = blockIdx.x * 256 + threadIdx.x;   // 0..327679 = 640*8*64
    int lane = gidx & 63;
    int kc = (gidx >> 6) & 7;
    int c16 = gidx >> 9;
    int col = c16 * 16 + (lane & 15);
    int k0 = kc * 32 + (lane >> 4) * 8;
    int r0 = 0, r1 = 0;
    if (col < C_CLS) {
      const float4 a = *(const float4*)(W + (size_t)col * D_DIM + k0);
      const float4 b = *(const float4*)(W + (size_t)col * D_DIM + k0 + 4);
      r0 = __builtin_amdgcn_cvt_pk_fp8_f32(a.x * 16.f, a.y * 16.f, 0, false);
      r0 = __builtin_amdgcn_cvt_pk_fp8_f32(a.z * 16.f, a.w * 16.f, r0, true);
      r1 = __builtin_amdgcn_cvt_pk_fp8_f32(b.x * 16.f, b.y * 16.f, 0, false);
      r1 = __builtin_amdgcn_cvt_pk_fp8_f32(b.z * 16.f, b.w * 16.f, r1, true);
    }
    size_t dst = (size_t)(c16 >> 1) * 8192 + (size_t)kc * 1024 +
                 (size_t)lane * 16 + (size_t)(c16 & 1) * 8;
    *(int2*)(WbF8 + dst) = (int2){r0, r1};
  } else {
    int row = (blockIdx.x - 1280) * 4 + (threadIdx.x >> 6);
    int l = threadIdx.x & 63;
    const float4 v = *(const float4*)(x + (size_t)row * D_DIM + l * 4);
    float ss = v.x * v.x + v.y * v.y + v.z * v.z + v.w * v.w;
#pragma unroll
    for (int m = 1; m < 64; m <<= 1) ss += __shfl_xor(ss, m, 64);
    float rn = 1.0f / sqrtf(ss);
    float s8 = rn * 8.f;
    int r0 = __builtin_amdgcn_cvt_pk_fp8_f32(v.x * s8, v.y * s8, 0, false);
    r0 = __builtin_amdgcn_cvt_pk_fp8_f32(v.z * s8, v.w * s8, r0, true);
    // this thread's 4 k-values: k0 = l*4 -> kc = l>>3
    int panel = row >> 7, r16 = (row >> 4) & 7, lr = row & 15;
    size_t dst = (size_t)panel * 32768 + (size_t)(r16 * 8 + (l >> 3)) * 512 +
                 (size_t)(((l >> 1) & 3) * 16 + lr) * 8 + (l & 1) * 4;
    *(int*)(xnb8 + dst) = r0;
    // exact fp32 target logit
    int tc = target[row];
    const float4 b = *(const float4*)(W + (size_t)tc * D_DIM + l * 4);
    float s = v.x * b.x + v.y * b.y + v.z * b.z + v.w * b.w;
#pragma unroll
    for (int m = 1; m < 64; m <<= 1) s += __shfl_xor(s, m, 64);
    if (l == 0) tgt[row] = s * rn;
  }
}

// ------- barrier-free fused fp8 GEMM + exp-sum, 3-DEEP B PIPELINE -------
// 1024 blocks (64 br x 8 cg x 2 sub), 256 thr = 4 waves (2wr x 2wc), wave tile
// 64x64 (acc 64 AGPR), 10 tiles-worth of cols split as 5 tiles of 128.
// launch_bounds(256,3): 168-reg cap fits acc(64) + FOUR B buffers (32 VGPR,
// 3-deep prefetch) + addressing -- r12..r18 were stuck at 1-deep under the
// (512,4) 128-reg cap, leaving B's L2 latency (~400-600cyc) exposed every
// window (issue-to-use = 1 window). 3-deep => issue-to-use ~3 windows,
// covered. Buffer<->kc map is static (kc&3); windows 5-7 prefetch the next
// tile's kc 0-2, so the epilogue adds cover at tile boundaries.
__global__ __launch_bounds__(256, 3) void k_gemm(const unsigned char* __restrict__ xnb8,
                                                 const unsigned char* __restrict__ WbF8,
                                                 float* __restrict__ partials) {
  __shared__ __align__(16) char lds[33792];   // A frags 32 KB @0; rsum 1 KB @32768
  const int b = blockIdx.x;
  const int cg = b & 7;                        // XCD colgroup 0..7
  const int sub = (b >> 3) & 1;                // 640-col half
  const int br = b >> 4;                       // row panel 0..63 (128 rows)
  const int t = threadIdx.x;
  const int w = t >> 6, l = t & 63;
  const int wr = w >> 1, wc = w & 1;           // 2M x 2N waves (64x64 tile)
  const int lr = l & 15, lk = l >> 4;
  float* rsumAll = (float*)(lds + 32768);      // [4 waves][64 rows]

  rsumAll[t] = 0.f;                            // covered by staging barrier

  // ---- stage A panel once: pure linear 32 KB copy into frag-order LDS ----
  {
    const char* Ag = (const char*)xnb8 + (size_t)br * 32768;
#pragma unroll
    for (int i = 0; i < 8; ++i)
      gl16(Ag + i * 4096 + w * 1024 + l * 16, lds + i * 4096 + w * 1024);
    asm volatile("s_waitcnt vmcnt(0)" ::: "memory");
    __builtin_amdgcn_sched_barrier(0);
    __builtin_amdgcn_s_barrier();
  }

  f32x4 acc[4][4];
#pragma unroll
  for (int m = 0; m < 4; m++)
#pragma unroll
    for (int n = 0; n < 4; n++) acc[m][n] = (f32x4){0.f, 0.f, 0.f, 0.f};

  // wave's A base in LDS (slot = (wr*4+fm)*8 + kc, 512 B each), per-lane
  const char* AwL = lds + (size_t)(wr * 4 * 8) * 512 + (size_t)l * 8;
  // wave's B base: pair index = cg*40 + sub*20 + wc*2; tile stride 32768
  const unsigned char* Bwv = WbF8 + (size_t)(cg * 40 + sub * 20 + wc * 2) * 8192 +
                             (size_t)l * 16;
  float* rw = rsumAll + w * 64;                // this wave's private rows

  // 4 B buffers (pair of uint4 each); prologue: kc 0,1,2 of tile 0 in flight
  uint4 pA0, pA1, pB0, pB1, pC0, pC1, pD0, pD1;
  pA0 = *(const uint4*)(Bwv);          pA1 = *(const uint4*)(Bwv + 8192);
  pB0 = *(const uint4*)(Bwv + 1024);   pB1 = *(const uint4*)(Bwv + 8192 + 1024);
  pC0 = *(const uint4*)(Bwv + 2048);   pC1 = *(const uint4*)(Bwv + 8192 + 2048);

  for (int s = 0; s < 5; ++s) {
    const unsigned char* Bt = Bwv + (size_t)s * 32768;
    const unsigned char* Btn = Bt + 32768;

    // window kc: consume cur buffer (kc&3), prefetch kc+3 into (kc+3)&3
    auto step = [&](int kc, uint4& c0, uint4& c1, uint4& p0, uint4& p1) {
      int kcp = kc + 3;
      if (kcp < 8) {
        p0 = *(const uint4*)(Bt + kcp * 1024);
        p1 = *(const uint4*)(Bt + 8192 + kcp * 1024);
      } else if (s < 4) {
        p0 = *(const uint4*)(Btn + (kcp - 8) * 1024);
        p1 = *(const uint4*)(Btn + 8192 + (kcp - 8) * 1024);
      }
      __builtin_amdgcn_s_setprio(1);
#pragma unroll
      for (int fm = 0; fm < 4; ++fm) {
        long a = u2l(*(const uint2*)(AwL + (fm * 8 + kc) * 512));
        acc[fm][0] = __builtin_amdgcn_mfma_f32_16x16x32_fp8_fp8(
            a, u2l((uint2){c0.x, c0.y}), acc[fm][0], 0, 0, 0);
        acc[fm][1] = __builtin_amdgcn_mfma_f32_16x16x32_fp8_fp8(
            a, u2l((uint2){c0.z, c0.w}), acc[fm][1], 0, 0, 0);
        acc[fm][2] = __builtin_amdgcn_mfma_f32_16x16x32_fp8_fp8(
            a, u2l((uint2){c1.x, c1.y}), acc[fm][2], 0, 0, 0);
        acc[fm][3] = __builtin_amdgcn_mfma_f32_16x16x32_fp8_fp8(
            a, u2l((uint2){c1.z, c1.w}), acc[fm][3], 0, 0, 0);
      }
      __builtin_amdgcn_s_setprio(0);
    };
    step(0, pA0, pA1, pD0, pD1);
    step(1, pB0, pB1, pA0, pA1);
    step(2, pC0, pC1, pB0, pB1);
    step(3, pD0, pD1, pC0, pC1);
    step(4, pA0, pA1, pD0, pD1);
    step(5, pB0, pB1, pA0, pA1);
    step(6, pC0, pC1, pB0, pB1);
    step(7, pD0, pD1, pC0, pC1);
    // after window7: bufs A,B,C hold next tile's kc 0,1,2 (loads in flight)

    // ---- per-tile epilogue: exp2, DPP col-reduce, accumulate into LDS rows ----
    // 16x16 C/D: col = lane&15, row = (lane>>4)*4 + j. No mask: padded cols
    // contribute exp2(0)=1, removed as a constant in k_loss1.
#pragma unroll
    for (int m = 0; m < 4; ++m) {
      float rs0 = 0.f, rs1 = 0.f, rs2 = 0.f, rs3 = 0.f;
#pragma unroll
      for (int n = 0; n < 4; ++n) {
        rs0 += __builtin_amdgcn_exp2f(acc[m][n][0] * S_L2E_SC);
        rs1 += __builtin_amdgcn_exp2f(acc[m][n][1] * S_L2E_SC);
        rs2 += __builtin_amdgcn_exp2f(acc[m][n][2] * S_L2E_SC);
        rs3 += __builtin_amdgcn_exp2f(acc[m][n][3] * S_L2E_SC);
        acc[m][n] = (f32x4){0.f, 0.f, 0.f, 0.f};
      }
      rs0 = row_sum16(rs0); rs1 = row_sum16(rs1);
      rs2 = row_sum16(rs2); rs3 = row_sum16(rs3);
      if (lr == 0) {
        int row = m * 16 + lk * 4;
        rw[row + 0] += rs0; rw[row + 1] += rs1;
        rw[row + 2] += rs2; rw[row + 3] += rs3;
      }
    }
  }

  // ---- final: combine 2 wc-waves per row, one coalesced store ----
  __syncthreads();
  if (t < 128) {
    int wr2 = t >> 6, r = t & 63;
    float sv = rsumAll[(wr2 * 2 + 0) * 64 + r] + rsumAll[(wr2 * 2 + 1) * 64 + r];
    partials[(size_t)(cg * 2 + sub) * N_ROWS + (size_t)br * 128 + t] = sv;
  }
}

// ---------------- per-row loss + block partial sums ----------------
__global__ __launch_bounds__(256) void k_loss1(const float* __restrict__ partials,
                                               const float* __restrict__ tgt,
                                               float* __restrict__ bsum) {
  __shared__ float wsum[4];
  int i = blockIdx.x * 256 + threadIdx.x;
  const float* p = partials + i;
  float s = -240.0f;   // remove padded cols 10000..10239 (W=0 -> exp term 1.0)
#pragma unroll
  for (int j = 0; j < NCB; ++j) s += p[(size_t)j * N_ROWS];
  float tl = tgt[i];
  float tcv = fminf(fmaxf(tl, -1.0f + 1e-7f), 1.0f - 1e-7f);
  const float cm = 0.95533648912560601964f;   // cos(0.3)
  const float sm = 0.29552020666133957510f;   // sin(0.3)
  float num = S_SCALE * (tcv * cm - sqrtf(fmaxf(1.0f - tcv * tcv, 0.f)) * sm);
  float sum_excl = s - __expf(S_SCALE * tl);
  float denom = __expf(num) + sum_excl;
  float L = num - __logf(denom);
#pragma unroll
  for (int m = 1; m < 64; m <<= 1) L += __shfl_xor(L, m, 64);
  int l = threadIdx.x & 63, w = threadIdx.x >> 6;
  if (l == 0) wsum[w] = L;
  __syncthreads();
  if (threadIdx.x == 0) bsum[blockIdx.x] = wsum[0] + wsum[1] + wsum[2] + wsum[3];
}

__global__ void k_loss2(const float* __restrict__ bsum, float* __restrict__ out) {
  float s = 0.f;
  for (int i = 0; i < 32; ++i) s += bsum[i];
  out[0] = -s / (float)N_ROWS;
}

// ---------------- launch ----------------
extern "C" void kernel_launch(void* const* d_in, const int* in_sizes, int n_in,
                              void* d_out, int out_size, void* d_ws, size_t ws_size,
                              hipStream_t stream) {
  const float* x = (const float*)d_in[0];
  const float* W = (const float*)d_in[1];
  const int* target = (const int*)d_in[2];
  float* out = (float*)d_out;
  char* ws = (char*)d_ws;

  unsigned char* xnb8 = (unsigned char*)(ws);               // 64*32768     = 2,097,152
  unsigned char* WbF8 = (unsigned char*)(ws + 2097152);     // 320*8192     = 2,621,440
  float* tgt = (float*)(ws + 4718592);                      // 8192*4
  float* partials = (float*)(ws + 4751360);                 // 16*8192*4    = 524,288
  float* bsum = (float*)(ws + 5275648);                     // 32*4

  k_prep<<<3328, 256, 0, stream>>>(x, W, target, xnb8, WbF8, tgt);
  k_gemm<<<1024, 256, 0, stream>>>(xnb8, WbF8, partials);
  k_loss1<<<32, 256, 0, stream>>>(partials, tgt, bsum);
  k_loss2<<<1, 1, 0, stream>>>(bsum, out);
}

// Round 20
// 48.650 us; speedup vs baseline: 1.0684x; 1.0684x over previous
//
#include <hip/hip_runtime.h>
#include <hip/hip_bf16.h>
#include <stdint.h>

#define S_SCALE 30.0f
#define A_QSCALE 2.70505320166681f  /* 30*log2(e)/16 : A*B product scale = 30*log2(e) */
#define N_ROWS 8192
#define D_DIM 256
#define C_CLS 10000
#define NCB 8

typedef __attribute__((ext_vector_type(4))) float f32x4;

static __device__ __forceinline__ void gl16(const void* g, void* l) {
  __builtin_amdgcn_global_load_lds(
      (const __attribute__((address_space(1))) void*)g,
      (__attribute__((address_space(3))) void*)l, 16, 0, 0);
}

static __device__ __forceinline__ long u2l(uint2 v) {
  union { uint2 u; long l; } x; x.u = v; return x.l;
}

// 16-lane (DPP-row) sum, VALU pipe only; all lanes receive the group sum.
static __device__ __forceinline__ float row_sum16(float v) {
  union { float f; int i; } u, w;
  u.f = v;
  w.i = __builtin_amdgcn_update_dpp(0, u.i, 0xB1, 0xF, 0xF, true);  u.f += w.f; // lane^1
  w.i = __builtin_amdgcn_update_dpp(0, u.i, 0x4E, 0xF, 0xF, true);  u.f += w.f; // lane^2
  w.i = __builtin_amdgcn_update_dpp(0, u.i, 0x141, 0xF, 0xF, true); u.f += w.f; // half-mirror
  w.i = __builtin_amdgcn_update_dpp(0, u.i, 0x140, 0xF, 0xF, true); u.f += w.f; // row-mirror
  return u.f;
}

// ---- fused prep (fp8 e4m3): blocks <1280 convert W (x16) to frag layout;
// rest L2-normalize x (x 30*log2e/16) into A-frag layout + exact fp32 target
// logit. Product scale of A,B fragments = 30*log2(e), so the GEMM accumulator
// is directly the exp2 argument (no per-element mul in the epilogue).
// WbF8: [c16 0..639][kc 0..7][lane]8B; lane=lk*16+lr holds W[col=c16*16+lr]
// [k=kc*32+lk*8 ..+8]; cols >= C_CLS zero (exp2(0)=1, subtracted in k_loss1).
// xnb8: [panel 0..63] 32KB frag blocks: byte (r16*8+kc)*512 + lane*8 within
// panel (row = panel*128 + r16*16 + lr).
__global__ __launch_bounds__(256) void k_prep(const float* __restrict__ x,
                                              const float* __restrict__ W,
                                              const int* __restrict__ target,
                                              unsigned char* __restrict__ xnb8,
                                              unsigned char* __restrict__ WbF8,
                                              float* __restrict__ tgt) {
  if (blockIdx.x < 1280) {
    int gidx = blockIdx.x * 256 + threadIdx.x;   // 0..327679 = 640*8*64
    int lane = gidx & 63;
    int kc = (gidx >> 6) & 7;
    int c16 = gidx >> 9;
    int col = c16 * 16 + (lane & 15);
    int k0 = kc * 32 + (lane >> 4) * 8;
    int r0 = 0, r1 = 0;
    if (col < C_CLS) {
      const float4 a = *(const float4*)(W + (size_t)col * D_DIM + k0);
      const float4 b = *(const float4*)(W + (size_t)col * D_DIM + k0 + 4);
      r0 = __builtin_amdgcn_cvt_pk_fp8_f32(a.x * 16.f, a.y * 16.f, 0, false);
      r0 = __builtin_amdgcn_cvt_pk_fp8_f32(a.z * 16.f, a.w * 16.f, r0, true);
      r1 = __builtin_amdgcn_cvt_pk_fp8_f32(b.x * 16.f, b.y * 16.f, 0, false);
      r1 = __builtin_amdgcn_cvt_pk_fp8_f32(b.z * 16.f, b.w * 16.f, r1, true);
    }
    *(int2*)(WbF8 + (size_t)gidx * 8) = (int2){r0, r1};
  } else {
    int row = (blockIdx.x - 1280) * 4 + (threadIdx.x >> 6);
    int l = threadIdx.x & 63;
    const float4 v = *(const float4*)(x + (size_t)row * D_DIM + l * 4);
    float ss = v.x * v.x + v.y * v.y + v.z * v.z + v.w * v.w;
#pragma unroll
    for (int m = 1; m < 64; m <<= 1) ss += __shfl_xor(ss, m, 64);
    float rn = 1.0f / sqrtf(ss);
    float s8 = rn * A_QSCALE;
    int r0 = __builtin_amdgcn_cvt_pk_fp8_f32(v.x * s8, v.y * s8, 0, false);
    r0 = __builtin_amdgcn_cvt_pk_fp8_f32(v.z * s8, v.w * s8, r0, true);
    // this thread's 4 k-values: k0 = l*4 -> kc = l>>3
    int panel = row >> 7, r16 = (row >> 4) & 7, lr = row & 15;
    size_t dst = (size_t)panel * 32768 + (size_t)(r16 * 8 + (l >> 3)) * 512 +
                 (size_t)(((l >> 1) & 3) * 16 + lr) * 8 + (l & 1) * 4;
    *(int*)(xnb8 + dst) = r0;
    // exact fp32 target logit
    int tc = target[row];
    const float4 b = *(const float4*)(W + (size_t)tc * D_DIM + l * 4);
    float s = v.x * b.x + v.y * b.y + v.z * b.z + v.w * b.w;
#pragma unroll
    for (int m = 1; m < 64; m <<= 1) s += __shfl_xor(s, m, 64);
    if (l == 0) tgt[row] = s * rn;
  }
}

// ------- barrier-free fused fp8 GEMM + exp-sum epilogue (r17 + VALU cuts) -------
// 512 blocks (2/CU), 8 waves (2Mx4N), wave tile 64x64, A panel 32 KB staged once.
// r20 deltas vs r17 (best, 42.3us): (1) exp scale folded into input quant ->
// epilogue is exp2(acc) directly (-64 v_mul/tile/thread feeding the trans op);
// (2) kc=0 window uses mfma(a,b,ZERO) -> no accumulator zeroing (-64
// v_accvgpr_write/tile). Both shrink the per-wave VALU stream that alternates
// with (and steals issue from) the MFMA pipe — the r17-r19 counters show
// MfmaUtil 40 + VALUBusy 38 with all latency levers null.
__global__ __launch_bounds__(512, 4) void k_gemm(const unsigned char* __restrict__ xnb8,
                                                 const unsigned char* __restrict__ WbF8,
                                                 float* __restrict__ partials) {
  __shared__ __align__(16) char lds[34816];   // A frags 32 KB @0; rsum 2 KB @32768
  const int b = blockIdx.x;
  const int cg = b & 7;                              // XCD colgroup 0..7
  const int br = b >> 3;                             // row panel 0..63 (128 rows)
  const int bc0 = cg * 5;                            // 5 consecutive 256-col tiles
  const int t = threadIdx.x;
  const int w = t >> 6, l = t & 63;
  const int wr = w >> 2, wc = w & 3;                 // 2M x 4N waves (64x64 tile)
  const int lr = l & 15, lk = l >> 4;
  float* rsumAll = (float*)(lds + 32768);            // [8 waves][64 rows]

  if (t < 512) rsumAll[t] = 0.f;                     // covered by staging barrier

  // ---- stage A panel once: pure linear 32 KB copy into frag-order LDS ----
  {
    const char* Ag = (const char*)xnb8 + (size_t)br * 32768;
#pragma unroll
    for (int i = 0; i < 4; ++i)
      gl16(Ag + i * 8192 + w * 1024 + l * 16, lds + i * 8192 + w * 1024);
    asm volatile("s_waitcnt vmcnt(0)" ::: "memory");
    __builtin_amdgcn_sched_barrier(0);
    __builtin_amdgcn_s_barrier();
  }

  f32x4 acc[4][4];
  const f32x4 z4 = (f32x4){0.f, 0.f, 0.f, 0.f};

  // wave's A base in LDS (slot = (wr*4+fm)*8 + kc, 512 B each), per-lane
  const char* AwL = lds + (size_t)(wr * 4 * 8) * 512 + (size_t)l * 8;
  // wave's B base in global frag layout (c16 = bc*16 + wc*4 + fn), per-lane
  const unsigned char* Bw = WbF8 + (size_t)(bc0 * 16 + wc * 4) * 4096 + (size_t)l * 8;
  float* rw = rsumAll + w * 64;                      // this wave's private rows

  uint2 b0[4], b1[4];
#pragma unroll
  for (int fn = 0; fn < 4; ++fn) b0[fn] = *(const uint2*)(Bw + fn * 4096);

  for (int tt = 0; tt < 5; ++tt) {
    auto step = [&](int kc, bool first, uint2(&cur)[4], uint2(&nxt)[4]) {
      if (kc < 7) {
#pragma unroll
        for (int fn = 0; fn < 4; ++fn)
          nxt[fn] = *(const uint2*)(Bw + fn * 4096 + (kc + 1) * 512);
      } else if (tt < 4) {
        // prefetch next tile's kc=0 under this tile's epilogue VALU
#pragma unroll
        for (int fn = 0; fn < 4; ++fn)
          nxt[fn] = *(const uint2*)(Bw + 65536 + fn * 4096);
      }
      __builtin_amdgcn_s_setprio(1);
#pragma unroll
      for (int fm = 0; fm < 4; ++fm) {
        long a = u2l(*(const uint2*)(AwL + (fm * 8 + kc) * 512));
#pragma unroll
        for (int fn = 0; fn < 4; ++fn)
          acc[fm][fn] = __builtin_amdgcn_mfma_f32_16x16x32_fp8_fp8(
              a, u2l(cur[fn]), first ? z4 : acc[fm][fn], 0, 0, 0);
      }
      __builtin_amdgcn_s_setprio(0);
    };
    step(0, true, b0, b1);  step(1, false, b1, b0);
    step(2, false, b0, b1); step(3, false, b1, b0);
    step(4, false, b0, b1); step(5, false, b1, b0);
    step(6, false, b0, b1); step(7, false, b1, b0);
    // after step7: b0 holds next tile's kc=0 frags (loads in flight)

    // ---- per-tile epilogue: exp2(acc) directly, DPP col-reduce, LDS rows ----
    // 16x16 C/D: col = lane&15, row = (lane>>4)*4 + j. No mask: padded cols
    // contribute exp2(0)=1, removed as a constant in k_loss1.
#pragma unroll
    for (int m = 0; m < 4; ++m) {
      float rs0 = 0.f, rs1 = 0.f, rs2 = 0.f, rs3 = 0.f;
#pragma unroll
      for (int n = 0; n < 4; ++n) {
        rs0 += __builtin_amdgcn_exp2f(acc[m][n][0]);
        rs1 += __builtin_amdgcn_exp2f(acc[m][n][1]);
        rs2 += __builtin_amdgcn_exp2f(acc[m][n][2]);
        rs3 += __builtin_amdgcn_exp2f(acc[m][n][3]);
      }
      rs0 = row_sum16(rs0); rs1 = row_sum16(rs1);
      rs2 = row_sum16(rs2); rs3 = row_sum16(rs3);
      if (lr == 0) {
        int row = m * 16 + lk * 4;
        rw[row + 0] += rs0; rw[row + 1] += rs1;
        rw[row + 2] += rs2; rw[row + 3] += rs3;
      }
    }
    Bw += 65536;   // next bc tile (16 colblks * 8 kc * 512 B)
  }

  // ---- final: combine 4 wc-waves per row, one coalesced store ----
  __syncthreads();
  if (t < 128) {
    int wr2 = t >> 6, r = t & 63;
    float sv = rsumAll[(wr2 * 4 + 0) * 64 + r] + rsumAll[(wr2 * 4 + 1) * 64 + r] +
               rsumAll[(wr2 * 4 + 2) * 64 + r] + rsumAll[(wr2 * 4 + 3) * 64 + r];
    partials[(size_t)cg * N_ROWS + (size_t)br * 128 + t] = sv;
  }
}

// ---------------- per-row loss + block partial sums ----------------
__global__ __launch_bounds__(256) void k_loss1(const float* __restrict__ partials,
                                               const float* __restrict__ tgt,
                                               float* __restrict__ bsum) {
  __shared__ float wsum[4];
  int i = blockIdx.x * 256 + threadIdx.x;
  const float* p = partials + i;
  float s = -240.0f;   // remove padded cols 10000..10239 (W=0 -> exp term 1.0)
#pragma unroll
  for (int j = 0; j < NCB; ++j) s += p[(size_t)j * N_ROWS];
  float tl = tgt[i];
  float tcv = fminf(fmaxf(tl, -1.0f + 1e-7f), 1.0f - 1e-7f);
  const float cm = 0.95533648912560601964f;   // cos(0.3)
  const float sm = 0.29552020666133957510f;   // sin(0.3)
  float num = S_SCALE * (tcv * cm - sqrtf(fmaxf(1.0f - tcv * tcv, 0.f)) * sm);
  float sum_excl = s - __expf(S_SCALE * tl);
  float denom = __expf(num) + sum_excl;
  float L = num - __logf(denom);
#pragma unroll
  for (int m = 1; m < 64; m <<= 1) L += __shfl_xor(L, m, 64);
  int l = threadIdx.x & 63, w = threadIdx.x >> 6;
  if (l == 0) wsum[w] = L;
  __syncthreads();
  if (threadIdx.x == 0) bsum[blockIdx.x] = wsum[0] + wsum[1] + wsum[2] + wsum[3];
}

__global__ void k_loss2(const float* __restrict__ bsum, float* __restrict__ out) {
  float s = 0.f;
  for (int i = 0; i < 32; ++i) s += bsum[i];
  out[0] = -s / (float)N_ROWS;
}

// ---------------- launch ----------------
extern "C" void kernel_launch(void* const* d_in, const int* in_sizes, int n_in,
                              void* d_out, int out_size, void* d_ws, size_t ws_size,
                              hipStream_t stream) {
  const float* x = (const float*)d_in[0];
  const float* W = (const float*)d_in[1];
  const int* target = (const int*)d_in[2];
  float* out = (float*)d_out;
  char* ws = (char*)d_ws;

  unsigned char* xnb8 = (unsigned char*)(ws);               // 64*32768     = 2,097,152
  unsigned char* WbF8 = (unsigned char*)(ws + 2097152);     // 640*4096     = 2,621,440
  float* tgt = (float*)(ws + 4718592);                      // 8192*4
  float* partials = (float*)(ws + 4751360);                 // 8*8192*4     = 262,144
  float* bsum = (float*)(ws + 5013504);                     // 32*4

  k_prep<<<3328, 256, 0, stream>>>(x, W, target, xnb8, WbF8, tgt);
  k_gemm<<<512, 512, 0, stream>>>(xnb8, WbF8, partials);
  k_loss1<<<32, 256, 0, stream>>>(partials, tgt, bsum);
  k_loss2<<<1, 1, 0, stream>>>(bsum, out);
}